// Round 2
// baseline (316.218 us; speedup 1.0000x reference)
//
#include <hip/hip_runtime.h>

#define KS 76      // Ks row stride (shorts): conflict-equivalent to baseline pattern
#define VS 140     // Vt row stride

typedef float f4  __attribute__((ext_vector_type(4)));
typedef short s8v __attribute__((ext_vector_type(8)));
typedef short s4v __attribute__((ext_vector_type(4)));

#define MFMA16(a, b, c) __builtin_amdgcn_mfma_f32_16x16x32_bf16((a), (b), (c), 0, 0, 0)

__device__ __forceinline__ unsigned short f2bf(float f) {
  union { float f; unsigned u; } x; x.f = f;
  unsigned r = x.u + 0x7FFFu + ((x.u >> 16) & 1u);   // RNE
  return (unsigned short)(r >> 16);
}
__device__ __forceinline__ float bf2f(unsigned short s) {
  union { unsigned u; float f; } x; x.u = ((unsigned)s) << 16; return x.f;
}
__device__ __forceinline__ s8v cvt8(const float* p) {
  float4 a = *(const float4*)p;
  float4 b = *(const float4*)(p + 4);
  s8v v;
  v[0] = (short)f2bf(a.x); v[1] = (short)f2bf(a.y);
  v[2] = (short)f2bf(a.z); v[3] = (short)f2bf(a.w);
  v[4] = (short)f2bf(b.x); v[5] = (short)f2bf(b.y);
  v[6] = (short)f2bf(b.z); v[7] = (short)f2bf(b.w);
  return v;
}
__device__ __forceinline__ unsigned pack2(float a, float b) {
  return (unsigned)f2bf(a) | ((unsigned)f2bf(b) << 16);
}
// Assemble an 8-bf16 MFMA operand from 4 packed dwords (lane-local, no shuffles).
__device__ __forceinline__ s8v mk8(unsigned a0, unsigned a1, unsigned b0, unsigned b1) {
  union { unsigned u[4]; s8v v; } r;
  r.u[0] = a0; r.u[1] = a1; r.u[2] = b0; r.u[3] = b1;
  return r.v;
}
// Two b64 LDS reads -> one 8-bf16 A-operand. Slot map: j0..3 from p0, j4..7 from p1.
__device__ __forceinline__ s8v ld44(const short* p0, const short* p1) {
  s4v a = *(const s4v*)p0;
  s4v b = *(const s4v*)(p1);
  s8v r;
  r[0] = a[0]; r[1] = a[1]; r[2] = a[2]; r[3] = a[3];
  r[4] = b[0]; r[5] = b[1]; r[6] = b[2]; r[7] = b[3];
  return r;
}

__global__ __launch_bounds__(256, 3)
void attn_head(const void* __restrict__ xg, const void* __restrict__ wqg,
               const void* __restrict__ wkg, const void* __restrict__ wvg,
               void* __restrict__ outg) {
  // LDS 37376 B (4 blocks/CU): Ks [128][76], Vt [64][140].
  __shared__ __align__(16) short smem[18688];
  short* Ksm = smem;            // K[s][h], h-contiguous
  short* Vt  = smem + 9728;     // V^T[h][s], s-contiguous

  const int tid  = threadIdx.x;
  const int wave = tid >> 6;
  const int lane = tid & 63;
  const int c16  = lane & 15;
  const int quad = lane >> 4;
  const int b    = blockIdx.x;

  // ---- inline dtype detect (replaces separate 1-block dispatch) ----
  // bf16 data read as bf16 -> ~100% plausible magnitudes; fp32 reinterpreted
  // as bf16 -> low halves are mantissa garbage (~55%). Sample 256 shorts of Wq.
  int ok;
  {
    const unsigned short* w = (const unsigned short*)wqg;
    float f = bf2f(w[tid]);
    float a = fabsf(f);
    ok = (f == 0.0f || (a >= 1e-4f && a <= 1e4f)) ? 1 : 0;
  }
  const int isbf = (__syncthreads_count(ok) >= 230) ? 1 : 0;

  const int mts[2] = {wave, 7 - wave};   // balanced causal split

  // ---- X fragments (serve as A for K/V and B for Q^T) ----
  s8v xf[2][2];
  #pragma unroll
  for (int mi = 0; mi < 2; mi++) {
    const size_t base = (size_t)b * (128 * 64) + (size_t)(mts[mi] * 16 + c16) * 64;
    #pragma unroll
    for (int kt = 0; kt < 2; kt++) {
      const int off = kt * 32 + quad * 8;
      if (isbf) xf[mi][kt] = *(const s8v*)((const unsigned short*)xg + base + off);
      else      xf[mi][kt] = cvt8((const float*)xg + base + off);
    }
  }

  // ---- phase 1: Q^T = Wq·X^T (regs), K,V -> LDS ----
  f4 QT[2][4];
  #pragma unroll
  for (int ht = 0; ht < 4; ht++) {
    s8v wqf[2], wkf[2], wvf[2];
    const int woff0 = (ht * 16 + c16) * 64 + quad * 8;
    #pragma unroll
    for (int kt = 0; kt < 2; kt++) {
      const int off = woff0 + kt * 32;
      if (isbf) {
        wqf[kt] = *(const s8v*)((const unsigned short*)wqg + off);
        wkf[kt] = *(const s8v*)((const unsigned short*)wkg + off);
        wvf[kt] = *(const s8v*)((const unsigned short*)wvg + off);
      } else {
        wqf[kt] = cvt8((const float*)wqg + off);
        wkf[kt] = cvt8((const float*)wkg + off);
        wvf[kt] = cvt8((const float*)wvg + off);
      }
    }
    #pragma unroll
    for (int mi = 0; mi < 2; mi++) {
      const int m = mts[mi];
      f4 z = {0.f, 0.f, 0.f, 0.f};
      f4 qt = z, kk = z, vv = z;
      qt = MFMA16(wqf[0], xf[mi][0], qt);  qt = MFMA16(wqf[1], xf[mi][1], qt);
      kk = MFMA16(xf[mi][0], wkf[0], kk);  kk = MFMA16(xf[mi][1], wkf[1], kk);
      vv = MFMA16(xf[mi][0], wvf[0], vv);  vv = MFMA16(xf[mi][1], wvf[1], vv);
      QT[mi][ht] = qt;
      #pragma unroll
      for (int r = 0; r < 4; r++)
        Ksm[(m * 16 + quad * 4 + r) * KS + ht * 16 + c16] = (short)f2bf(kk[r]);
      s4v pv;
      pv[0] = (short)f2bf(vv[0]); pv[1] = (short)f2bf(vv[1]);
      pv[2] = (short)f2bf(vv[2]); pv[3] = (short)f2bf(vv[3]);
      *(s4v*)(Vt + (ht * 16 + c16) * VS + m * 16 + quad * 4) = pv;
    }
  }

  // ---- Q B-operand frags, packed lane-local BEFORE the barrier ----
  // MFMA contraction is slot-aligned: slot (quad,j) -> h = (j<4?2hp:2hp+1)*16
  // + quad*4 + (j&3). Q^T C-layout (lane holds h=ht*16+quad*4+r, col c16)
  // matches this map directly -> no cross-lane regroup needed. K (A-operand)
  // is read from LDS at the SAME slot map below. Scale 1/8 folded in.
  s8v qb[2][2];
  #pragma unroll
  for (int mi = 0; mi < 2; mi++)
    #pragma unroll
    for (int hp = 0; hp < 2; hp++)
      qb[mi][hp] = mk8(
          pack2(QT[mi][2*hp][0]   * 0.125f, QT[mi][2*hp][1]   * 0.125f),
          pack2(QT[mi][2*hp][2]   * 0.125f, QT[mi][2*hp][3]   * 0.125f),
          pack2(QT[mi][2*hp+1][0] * 0.125f, QT[mi][2*hp+1][1] * 0.125f),
          pack2(QT[mi][2*hp+1][2] * 0.125f, QT[mi][2*hp+1][3] * 0.125f));

  __syncthreads();   // only barrier (besides the detect count)

  // ---- phase 2 per M-tile: S^T -> exp/sum -> O^T = V^T·P^T ----
  #pragma unroll
  for (int mi = 0; mi < 2; mi++) {
    const int m = mts[mi];

    // S^T tiles: rows = keys (nt), cols = this M-tile's 16 queries
    f4 S[8];
    #pragma unroll
    for (int nt = 0; nt < 8; nt++) {
      if (nt > m) continue;                 // wave-uniform causal skip
      const short* kr = Ksm + (nt * 16 + c16) * KS + quad * 4;
      f4 s = {0.f, 0.f, 0.f, 0.f};
      s = MFMA16(ld44(kr,      kr + 16), qb[mi][0], s);   // h 0..31 slots
      s = MFMA16(ld44(kr + 32, kr + 48), qb[mi][1], s);   // h 32..63 slots
      S[nt] = s;
    }

    // exp + per-query sum (query = c16 column; only 2 shuffles)
    float sum = 0.f;
    #pragma unroll
    for (int nt = 0; nt < 8; nt++) {
      if (nt > m) continue;
      #pragma unroll
      for (int r = 0; r < 4; r++) {
        const bool keep = (nt < m) || (quad * 4 + r <= c16);
        float e = keep ? __expf(S[nt][r]) : 0.0f;
        S[nt][r] = e;
        sum += e;
      }
    }
    sum += __shfl_xor(sum, 16);
    sum += __shfl_xor(sum, 32);
    const float inv = 1.0f / sum;           // normalize in epilogue

    // P^T packed lane-local: C-layout rows quad*4+r ARE the slot map rows.
    unsigned ppk[8][2];
    #pragma unroll
    for (int nt = 0; nt < 8; nt++) {
      if (nt > m) continue;
      ppk[nt][0] = pack2(S[nt][0], S[nt][1]);
      ppk[nt][1] = pack2(S[nt][2], S[nt][3]);
    }

    f4 acc[4];
    #pragma unroll
    for (int ht = 0; ht < 4; ht++) { f4 z = {0.f,0.f,0.f,0.f}; acc[ht] = z; }
    const int nchunk = (m >> 1) + 1;
    #pragma unroll
    for (int kt = 0; kt < 4; kt++) {
      if (kt >= nchunk) continue;           // wave-uniform causal K-range
      const bool hb = (2 * kt + 1) <= m;
      const s8v pb = mk8(ppk[2 * kt][0], ppk[2 * kt][1],
                         hb ? ppk[2 * kt + 1][0] : 0u,
                         hb ? ppk[2 * kt + 1][1] : 0u);
      #pragma unroll
      for (int ht = 0; ht < 4; ht++) {
        const short* vr = Vt + (ht * 16 + c16) * VS + kt * 32 + quad * 4;
        acc[ht] = MFMA16(ld44(vr, vr + 16), pb, acc[ht]);
      }
    }

    // epilogue: O^T lane holds 4 consecutive h for query t=c16 -> 16B stores
    if (isbf) {
      unsigned short* op = (unsigned short*)outg + (size_t)b * (128 * 64);
      #pragma unroll
      for (int ht = 0; ht < 4; ht++) {
        s4v o;
        o[0] = (short)f2bf(acc[ht][0] * inv); o[1] = (short)f2bf(acc[ht][1] * inv);
        o[2] = (short)f2bf(acc[ht][2] * inv); o[3] = (short)f2bf(acc[ht][3] * inv);
        *(s4v*)(op + (size_t)(m * 16 + c16) * 64 + ht * 16 + quad * 4) = o;
      }
    } else {
      float* op = (float*)outg + (size_t)b * (128 * 64);
      #pragma unroll
      for (int ht = 0; ht < 4; ht++) {
        float4 o = {acc[ht][0] * inv, acc[ht][1] * inv,
                    acc[ht][2] * inv, acc[ht][3] * inv};
        *(float4*)(op + (size_t)(m * 16 + c16) * 64 + ht * 16 + quad * 4) = o;
      }
    }
  }
}

extern "C" void kernel_launch(void* const* d_in, const int* in_sizes, int n_in,
                              void* d_out, int out_size, void* d_ws, size_t ws_size,
                              hipStream_t stream) {
  (void)d_ws; (void)ws_size; (void)in_sizes; (void)n_in; (void)out_size;
  attn_head<<<dim3(4096), dim3(256), 0, stream>>>(
      d_in[0], d_in[1], d_in[2], d_in[3], d_out);
}